// Round 13
// baseline (2519.658 us; speedup 1.0000x reference)
//
#include <hip/hip_runtime.h>

#define CUBE 32

typedef _Float16 half2_t __attribute__((ext_vector_type(2)));

__device__ __forceinline__ float sgpr_f(float v) {
    int i = __builtin_amdgcn_readfirstlane(__float_as_int(v));
    return __int_as_float(i);
}

// ---------------- Kernel A: surface = x @ W_in^T + b_in ----------------
__global__ __launch_bounds__(256) void in_gemm(
    const float* __restrict__ x,
    const float* __restrict__ W_in,
    const float* __restrict__ b_in,
    float* __restrict__ surface)
{
    __shared__ __align__(16) float As[16][68];
    __shared__ __align__(16) float Bs[16][68];
    const int t  = threadIdx.x;
    const int tx = t & 15, ty = t >> 4;
    const int bn = blockIdx.x * 64;
    const int bb = blockIdx.y * 64;

    float acc[4][4];
#pragma unroll
    for (int i = 0; i < 4; ++i)
#pragma unroll
        for (int j = 0; j < 4; ++j) acc[i][j] = 0.0f;

    for (int k0 = 0; k0 < 784; k0 += 16) {
        const int e  = t * 4;
        const int r  = e >> 4;
        const int kk = e & 15;
        float4 av = *(const float4*)&x[(size_t)(bb + r) * 784 + k0 + kk];
        float4 bv = *(const float4*)&W_in[(size_t)(bn + r) * 784 + k0 + kk];
        As[kk + 0][r] = av.x; As[kk + 1][r] = av.y; As[kk + 2][r] = av.z; As[kk + 3][r] = av.w;
        Bs[kk + 0][r] = bv.x; Bs[kk + 1][r] = bv.y; Bs[kk + 2][r] = bv.z; Bs[kk + 3][r] = bv.w;
        __syncthreads();
#pragma unroll
        for (int kki = 0; kki < 16; ++kki) {
            float4 a = *(const float4*)&As[kki][ty * 4];
            float4 b = *(const float4*)&Bs[kki][tx * 4];
            float aa[4] = {a.x, a.y, a.z, a.w};
            float bbv[4] = {b.x, b.y, b.z, b.w};
#pragma unroll
            for (int i = 0; i < 4; ++i)
#pragma unroll
                for (int j = 0; j < 4; ++j)
                    acc[i][j] = fmaf(aa[i], bbv[j], acc[i][j]);
        }
        __syncthreads();
    }
#pragma unroll
    for (int i = 0; i < 4; ++i) {
        const int row = bb + ty * 4 + i;
#pragma unroll
        for (int j = 0; j < 4; ++j) {
            const int col = bn + tx * 4 + j;
            surface[(size_t)row * 1024 + col] = acc[i][j] + b_in[col];
        }
    }
}

// ---------------- Kernel B: TWO-cube f16-state evolution + output GEMM --------
// 512 thr (16 tx × 32 ty); each block evolves cubes 2b and 2b+1 together.
// State: _Float16 S[2][32][34][36] = 153 KB (y-halo rows 0/33, x-halo cols
// 0/33, cols 34-35 pad; stride 36 halfs = 72 B keeps half2 reads 4B-aligned).
// Math: f32 scalar fmaf on cvt'd halfs (r9's regression was fdot2 rate +
// layout conflicts, NOT f16 storage — f16 state passed at absmax 2e-3).
// Schedule: r11's proven 4-deep in-place write pipeline, barrier every 4
// phases. Two cubes amortize per-phase overhead (nbias load, barrier, loop,
// dependency tails) 2x, and block-rounds drop 4 -> 2 (512 blocks).

#define REP32(M) M(0)M(1)M(2)M(3)M(4)M(5)M(6)M(7)M(8)M(9)M(10)M(11)M(12)M(13)M(14)M(15)M(16)M(17)M(18)M(19)M(20)M(21)M(22)M(23)M(24)M(25)M(26)M(27)M(28)M(29)M(30)M(31)

// out0 (x=2tx): l,c,r = r0,r1,r2 ; out1 (x=2tx+1): r1,r2,r3
#define RW(aL, aR, wl, wc, wr, r0, r1, r2, r3)                                 \
    aL = fmaf(wl, r0, aL); aL = fmaf(wc, r1, aL); aL = fmaf(wr, r2, aL);       \
    aR = fmaf(wl, r1, aR); aR = fmaf(wc, r2, aR); aR = fmaf(wr, r3, aR);

// One cube's phase-p work. Window rows read as aligned half2 pairs
// ([tx2],[tx2+2]); owned voxels at cols tx2+1, tx2+2 written as 2x b16.
#define PLANE_C(c, p, q, w4, SF0, SF1, aN0, aN1, aC0, aC1, aP0, aP1,           \
                PD0, PD1, CC0, CC1) {                                          \
    const half2_t ha0 = *(const half2_t*)&S[c][p][ty + 0][tx2];                \
    const half2_t hb0 = *(const half2_t*)&S[c][p][ty + 0][tx2 + 2];            \
    const half2_t ha1 = *(const half2_t*)&S[c][p][ty + 1][tx2];                \
    const half2_t hb1 = *(const half2_t*)&S[c][p][ty + 1][tx2 + 2];            \
    const half2_t ha2 = *(const half2_t*)&S[c][p][ty + 2][tx2];                \
    const half2_t hb2 = *(const half2_t*)&S[c][p][ty + 2][tx2 + 2];            \
    const float r00 = (float)ha0.x, r01 = (float)ha0.y,                        \
                r02 = (float)hb0.x, r03 = (float)hb0.y;                        \
    const float r10 = (float)ha1.x, r11 = (float)ha1.y,                        \
                r12 = (float)hb1.x, r13 = (float)hb1.y;                        \
    const float r20 = (float)ha2.x, r21 = (float)ha2.y,                        \
                r22 = (float)hb2.x, r23 = (float)hb2.y;                        \
    if ((p) >= 4) {                                                            \
        S[c][w4][ty + 1][tx2 + 1] = (_Float16)PD0;                             \
        S[c][w4][ty + 1][tx2 + 2] = (_Float16)PD1;                             \
    }                                                                          \
    if ((p) < 31) {                                                            \
        RW(aN0, aN1, cw0, cw1, cw2, r00, r01, r02, r03)                        \
        RW(aN0, aN1, cw3, cw4, cw5, r10, r11, r12, r13)                        \
        RW(aN0, aN1, cw6, cw7, cw8, r20, r21, r22, r23)                        \
    }                                                                          \
    RW(aC0, aC1, cw9,  cw10, cw11, r00, r01, r02, r03)                         \
    RW(aC0, aC1, cw12, cw13, cw14, r10, r11, r12, r13)                         \
    RW(aC0, aC1, cw15, cw16, cw17, r20, r21, r22, r23)                         \
    if ((p) >= 1) {                                                            \
        RW(aP0, aP1, cw18, cw19, cw20, r00, r01, r02, r03)                     \
        RW(aP0, aP1, cw21, cw22, cw23, r10, r11, r12, r13)                     \
        RW(aP0, aP1, cw24, cw25, cw26, r20, r21, r22, r23)                     \
        const float pre0 = aP0 + nbq.x + (((q) == 0) ? SF0 : 0.0f);            \
        const float pre1 = aP1 + nbq.y + (((q) == 0) ? SF1 : 0.0f);            \
        const float h0 = 1.0f - 2.0f * __builtin_amdgcn_rcpf(                  \
            __builtin_amdgcn_exp2f(pre0 * 2.8853900817779268f) + 1.0f);        \
        const float h1 = 1.0f - 2.0f * __builtin_amdgcn_rcpf(                  \
            __builtin_amdgcn_exp2f(pre1 * 2.8853900817779268f) + 1.0f);        \
        PD0 = 0.5f * (CC0 + h0);                                               \
        PD1 = 0.5f * (CC1 + h1);                                               \
        aP0 = 0.0f; aP1 = 0.0f;                                                \
    }                                                                          \
    CC0 = r11; CC1 = r12;                                                      \
}

// Phase p for BOTH cubes. sN/sC/sP = accumulator slot indices ((p+1)%3, p%3,
// (p+2)%3); w4 = plane p-4 (pending LDS write); q = p-1 (finalize target).
#define PLANE(p, q, w4, sN, sC, sP) {                                          \
    if ((p) % 4 == 0) __syncthreads();                                         \
    nb_##p = *(const float2*)&nbias[(p) * 1024 + nboff];                       \
    const float2 nbq = nb_##q;                                                 \
    PLANE_C(0, p, q, w4, sfA0, sfA1,                                           \
            aA##sN##0, aA##sN##1, aA##sC##0, aA##sC##1, aA##sP##0, aA##sP##1,  \
            pdA##sP##0, pdA##sP##1, ccA0, ccA1)                                \
    PLANE_C(1, p, q, w4, sfB0, sfB1,                                           \
            aB##sN##0, aB##sN##1, aB##sC##0, aB##sC##1, aB##sP##0, aB##sP##1,  \
            pdB##sP##0, pdB##sP##1, ccB0, ccB1)                                \
}

__global__ __launch_bounds__(512) void cube_evolve(
    const float* __restrict__ surface,   // [1024][1024]
    const float* __restrict__ conv_w,    // [27]  (kd,ky,kx)
    const float* __restrict__ nbias,     // [32768] (d,y,x)
    const float* __restrict__ W_out,     // [10][32768]
    const float* __restrict__ b_out,     // [10]
    const int*   __restrict__ steps_p,   // [1]
    float* __restrict__ out)             // [1024][10]
{
    __shared__ __align__(16) _Float16 S[2][32][34][36];   // 156,672 B
    __shared__ float red[2][10][8];

    const int b0  = blockIdx.x * 2;      // cube A batch index
    const int b1  = b0 + 1;              // cube B batch index
    const int tx  = threadIdx.x;         // 0..15, owns x = 2tx, 2tx+1
    const int ty  = threadIdx.y;         // 0..31
    const int tid = ty * 16 + tx;
    const int tx2 = tx * 2;              // window base (halo coord x' = x+1)
    const int nboff = ty * 32 + tx2;
    const int steps = steps_p[0];

    // zero both cubes + halos + pads
    for (int i = tid; i < 2 * 32 * 34 * 36 / 2; i += 512) ((int*)S)[i] = 0;

    // conv weights -> uniform scalars (SGPRs)
    const float cw0  = sgpr_f(conv_w[0]),  cw1  = sgpr_f(conv_w[1]),  cw2  = sgpr_f(conv_w[2]);
    const float cw3  = sgpr_f(conv_w[3]),  cw4  = sgpr_f(conv_w[4]),  cw5  = sgpr_f(conv_w[5]);
    const float cw6  = sgpr_f(conv_w[6]),  cw7  = sgpr_f(conv_w[7]),  cw8  = sgpr_f(conv_w[8]);
    const float cw9  = sgpr_f(conv_w[9]),  cw10 = sgpr_f(conv_w[10]), cw11 = sgpr_f(conv_w[11]);
    const float cw12 = sgpr_f(conv_w[12]), cw13 = sgpr_f(conv_w[13]), cw14 = sgpr_f(conv_w[14]);
    const float cw15 = sgpr_f(conv_w[15]), cw16 = sgpr_f(conv_w[16]), cw17 = sgpr_f(conv_w[17]);
    const float cw18 = sgpr_f(conv_w[18]), cw19 = sgpr_f(conv_w[19]), cw20 = sgpr_f(conv_w[20]);
    const float cw21 = sgpr_f(conv_w[21]), cw22 = sgpr_f(conv_w[22]), cw23 = sgpr_f(conv_w[23]);
    const float cw24 = sgpr_f(conv_w[24]), cw25 = sgpr_f(conv_w[25]), cw26 = sgpr_f(conv_w[26]);

    const float2 sfvA = *(const float2*)&surface[(size_t)b0 * 1024 + nboff];
    const float2 sfvB = *(const float2*)&surface[(size_t)b1 * 1024 + nboff];
    const float sfA0 = sfvA.x, sfA1 = sfvA.y;
    const float sfB0 = sfvB.x, sfB1 = sfvB.y;

    for (int st = 0; st < steps; ++st) {
#define DECL_NB(d) float2 nb_##d;
        REP32(DECL_NB)
#undef DECL_NB
        // accumulator slots (3) × 2 voxels × 2 cubes
        float aA00 = 0.f, aA01 = 0.f, aA10 = 0.f, aA11 = 0.f, aA20 = 0.f, aA21 = 0.f;
        float aB00 = 0.f, aB01 = 0.f, aB10 = 0.f, aB11 = 0.f, aB20 = 0.f, aB21 = 0.f;
        // pend slots (3) × 2 voxels × 2 cubes
        float pdA00 = 0.f, pdA01 = 0.f, pdA10 = 0.f, pdA11 = 0.f, pdA20 = 0.f, pdA21 = 0.f;
        float pdB00 = 0.f, pdB01 = 0.f, pdB10 = 0.f, pdB11 = 0.f, pdB20 = 0.f, pdB21 = 0.f;
        float ccA0 = 0.f, ccA1 = 0.f, ccB0 = 0.f, ccB1 = 0.f;

        PLANE( 0,  0,  0, 1, 0, 2)
        PLANE( 1,  0,  0, 2, 1, 0)
        PLANE( 2,  1,  0, 0, 2, 1)
        PLANE( 3,  2,  0, 1, 0, 2)
        PLANE( 4,  3,  0, 2, 1, 0)
        PLANE( 5,  4,  1, 0, 2, 1)
        PLANE( 6,  5,  2, 1, 0, 2)
        PLANE( 7,  6,  3, 2, 1, 0)
        PLANE( 8,  7,  4, 0, 2, 1)
        PLANE( 9,  8,  5, 1, 0, 2)
        PLANE(10,  9,  6, 2, 1, 0)
        PLANE(11, 10,  7, 0, 2, 1)
        PLANE(12, 11,  8, 1, 0, 2)
        PLANE(13, 12,  9, 2, 1, 0)
        PLANE(14, 13, 10, 0, 2, 1)
        PLANE(15, 14, 11, 1, 0, 2)
        PLANE(16, 15, 12, 2, 1, 0)
        PLANE(17, 16, 13, 0, 2, 1)
        PLANE(18, 17, 14, 1, 0, 2)
        PLANE(19, 18, 15, 2, 1, 0)
        PLANE(20, 19, 16, 0, 2, 1)
        PLANE(21, 20, 17, 1, 0, 2)
        PLANE(22, 21, 18, 2, 1, 0)
        PLANE(23, 22, 19, 0, 2, 1)
        PLANE(24, 23, 20, 1, 0, 2)
        PLANE(25, 24, 21, 2, 1, 0)
        PLANE(26, 25, 22, 0, 2, 1)
        PLANE(27, 26, 23, 1, 0, 2)
        PLANE(28, 27, 24, 2, 1, 0)
        PLANE(29, 28, 25, 0, 2, 1)
        PLANE(30, 29, 26, 1, 0, 2)
        PLANE(31, 30, 27, 2, 1, 0)
        { // tail: output 31 accumulates in slot 1 (phase30 aN + phase31 aC);
          // flush pending planes 28(slot1), 29(slot2), 30(slot0), 31.
            const float preA0 = aA10 + nb_31.x;
            const float preA1 = aA11 + nb_31.y;
            const float preB0 = aB10 + nb_31.x;
            const float preB1 = aB11 + nb_31.y;
            const float hA0 = 1.0f - 2.0f * __builtin_amdgcn_rcpf(
                __builtin_amdgcn_exp2f(preA0 * 2.8853900817779268f) + 1.0f);
            const float hA1 = 1.0f - 2.0f * __builtin_amdgcn_rcpf(
                __builtin_amdgcn_exp2f(preA1 * 2.8853900817779268f) + 1.0f);
            const float hB0 = 1.0f - 2.0f * __builtin_amdgcn_rcpf(
                __builtin_amdgcn_exp2f(preB0 * 2.8853900817779268f) + 1.0f);
            const float hB1 = 1.0f - 2.0f * __builtin_amdgcn_rcpf(
                __builtin_amdgcn_exp2f(preB1 * 2.8853900817779268f) + 1.0f);
            const float vA0 = 0.5f * (ccA0 + hA0), vA1 = 0.5f * (ccA1 + hA1);
            const float vB0 = 0.5f * (ccB0 + hB0), vB1 = 0.5f * (ccB1 + hB1);
            __syncthreads();   // waves may still be reading planes 28..31
            S[0][28][ty + 1][tx2 + 1] = (_Float16)pdA10;
            S[0][28][ty + 1][tx2 + 2] = (_Float16)pdA11;
            S[0][29][ty + 1][tx2 + 1] = (_Float16)pdA20;
            S[0][29][ty + 1][tx2 + 2] = (_Float16)pdA21;
            S[0][30][ty + 1][tx2 + 1] = (_Float16)pdA00;
            S[0][30][ty + 1][tx2 + 2] = (_Float16)pdA01;
            S[0][31][ty + 1][tx2 + 1] = (_Float16)vA0;
            S[0][31][ty + 1][tx2 + 2] = (_Float16)vA1;
            S[1][28][ty + 1][tx2 + 1] = (_Float16)pdB10;
            S[1][28][ty + 1][tx2 + 2] = (_Float16)pdB11;
            S[1][29][ty + 1][tx2 + 1] = (_Float16)pdB20;
            S[1][29][ty + 1][tx2 + 2] = (_Float16)pdB21;
            S[1][30][ty + 1][tx2 + 1] = (_Float16)pdB00;
            S[1][30][ty + 1][tx2 + 2] = (_Float16)pdB01;
            S[1][31][ty + 1][tx2 + 1] = (_Float16)vB0;
            S[1][31][ty + 1][tx2 + 2] = (_Float16)vB1;
        }
    }
    __syncthreads();   // state complete & visible

    // ---- fused output GEMM for both cubes; W_out loaded once, used twice
    float pA0 = 0.f, pA1 = 0.f, pA2 = 0.f, pA3 = 0.f, pA4 = 0.f;
    float pA5 = 0.f, pA6 = 0.f, pA7 = 0.f, pA8 = 0.f, pA9 = 0.f;
    float pB0 = 0.f, pB1 = 0.f, pB2 = 0.f, pB3 = 0.f, pB4 = 0.f;
    float pB5 = 0.f, pB6 = 0.f, pB7 = 0.f, pB8 = 0.f, pB9 = 0.f;
    const int base = tid * 4;
#pragma unroll 4
    for (int j = 0; j < 16; ++j) {
        const int idx = base + j * 2048;
        const int d   = idx >> 10;
        const int rem = idx & 1023;
        const int yy  = rem >> 5;
        const int xx  = rem & 31;          // multiple of 4
        // values at global x = xx..xx+3 live at cols xx+1..xx+4
        const half2_t hA0 = *(const half2_t*)&S[0][d][yy + 1][xx];
        const half2_t hA1 = *(const half2_t*)&S[0][d][yy + 1][xx + 2];
        const half2_t hA2 = *(const half2_t*)&S[0][d][yy + 1][xx + 4];
        const half2_t hB0 = *(const half2_t*)&S[1][d][yy + 1][xx];
        const half2_t hB1 = *(const half2_t*)&S[1][d][yy + 1][xx + 2];
        const half2_t hB2 = *(const half2_t*)&S[1][d][yy + 1][xx + 4];
        const float sA0v = (float)hA0.y, sA1v = (float)hA1.x,
                    sA2v = (float)hA1.y, sA3v = (float)hA2.x;
        const float sB0v = (float)hB0.y, sB1v = (float)hB1.x,
                    sB2v = (float)hB1.y, sB3v = (float)hB2.x;
#define OACC(o) { const float4 wv = *(const float4*)&W_out[(size_t)(o) * 32768 + idx]; \
        pA##o = fmaf(sA0v, wv.x, pA##o); pA##o = fmaf(sA1v, wv.y, pA##o);      \
        pA##o = fmaf(sA2v, wv.z, pA##o); pA##o = fmaf(sA3v, wv.w, pA##o);      \
        pB##o = fmaf(sB0v, wv.x, pB##o); pB##o = fmaf(sB1v, wv.y, pB##o);      \
        pB##o = fmaf(sB2v, wv.z, pB##o); pB##o = fmaf(sB3v, wv.w, pB##o); }
        OACC(0) OACC(1) OACC(2) OACC(3) OACC(4)
        OACC(5) OACC(6) OACC(7) OACC(8) OACC(9)
#undef OACC
    }

    const int lane = tid & 63, wvi = tid >> 6;
#define RED(c, o, pv) { float t = pv;                                          \
    t += __shfl_down(t, 32, 64); t += __shfl_down(t, 16, 64);                  \
    t += __shfl_down(t, 8, 64);  t += __shfl_down(t, 4, 64);                   \
    t += __shfl_down(t, 2, 64);  t += __shfl_down(t, 1, 64);                   \
    if (lane == 0) red[c][o][wvi] = t; }
    RED(0, 0, pA0) RED(0, 1, pA1) RED(0, 2, pA2) RED(0, 3, pA3) RED(0, 4, pA4)
    RED(0, 5, pA5) RED(0, 6, pA6) RED(0, 7, pA7) RED(0, 8, pA8) RED(0, 9, pA9)
    RED(1, 0, pB0) RED(1, 1, pB1) RED(1, 2, pB2) RED(1, 3, pB3) RED(1, 4, pB4)
    RED(1, 5, pB5) RED(1, 6, pB6) RED(1, 7, pB7) RED(1, 8, pB8) RED(1, 9, pB9)
#undef RED
    __syncthreads();
    if (tid < 10) {
        float sumA = b_out[tid], sumB = b_out[tid];
#pragma unroll
        for (int w8 = 0; w8 < 8; ++w8) {
            sumA += red[0][tid][w8];
            sumB += red[1][tid][w8];
        }
        out[(size_t)b0 * 10 + tid] = sumA;
        out[(size_t)b1 * 10 + tid] = sumB;
    }
}

// ---------------- launcher ----------------
extern "C" void kernel_launch(void* const* d_in, const int* in_sizes, int n_in,
                              void* d_out, int out_size, void* d_ws, size_t ws_size,
                              hipStream_t stream) {
    const float* x      = (const float*)d_in[0];
    const float* W_in   = (const float*)d_in[1];
    const float* b_in   = (const float*)d_in[2];
    const float* conv_w = (const float*)d_in[3];
    const float* nbias  = (const float*)d_in[4];
    const float* W_out  = (const float*)d_in[5];
    const float* b_out  = (const float*)d_in[6];
    const int*   steps  = (const int*)d_in[7];
    float* out = (float*)d_out;
    float* surface = (float*)d_ws;   // 1024*1024 f32 = 4 MB scratch

    in_gemm<<<dim3(16, 16), 256, 0, stream>>>(x, W_in, b_in, surface);
    cube_evolve<<<512, dim3(16, 32), 0, stream>>>(surface, conv_w, nbias,
                                                  W_out, b_out, steps, out);
}

// Round 14
// 1205.009 us; speedup vs baseline: 2.0910x; 2.0910x over previous
//
#include <hip/hip_runtime.h>

#define CUBE 32

__device__ __forceinline__ float sgpr_f(float v) {
    int i = __builtin_amdgcn_readfirstlane(__float_as_int(v));
    return __int_as_float(i);
}
// 16-lane-row DPP shifts with bound_ctrl=1 (out-of-row lanes read 0).
// DPP rows (16 lanes) == our tx dimension (16 threads), so row edges are
// exactly the x=0 / x=31 cube boundary -> hardware zero-fill = zero halo.
// (r6's bug: wave_shr1 0x138 crossed ty rows at lanes 16/32/48.)
__device__ __forceinline__ float row_shr1(float v) {   // lane tx <- tx-1; tx=0 -> 0
    return __int_as_float(__builtin_amdgcn_update_dpp(
        0, __float_as_int(v), 0x111, 0xF, 0xF, true));
}
__device__ __forceinline__ float row_shl1(float v) {   // lane tx <- tx+1; tx=15 -> 0
    return __int_as_float(__builtin_amdgcn_update_dpp(
        0, __float_as_int(v), 0x101, 0xF, 0xF, true));
}

// ---------------- Kernel A: surface = x @ W_in^T + b_in ----------------
__global__ __launch_bounds__(256) void in_gemm(
    const float* __restrict__ x,
    const float* __restrict__ W_in,
    const float* __restrict__ b_in,
    float* __restrict__ surface)
{
    __shared__ __align__(16) float As[16][68];
    __shared__ __align__(16) float Bs[16][68];
    const int t  = threadIdx.x;
    const int tx = t & 15, ty = t >> 4;
    const int bn = blockIdx.x * 64;
    const int bb = blockIdx.y * 64;

    float acc[4][4];
#pragma unroll
    for (int i = 0; i < 4; ++i)
#pragma unroll
        for (int j = 0; j < 4; ++j) acc[i][j] = 0.0f;

    for (int k0 = 0; k0 < 784; k0 += 16) {
        const int e  = t * 4;
        const int r  = e >> 4;
        const int kk = e & 15;
        float4 av = *(const float4*)&x[(size_t)(bb + r) * 784 + k0 + kk];
        float4 bv = *(const float4*)&W_in[(size_t)(bn + r) * 784 + k0 + kk];
        As[kk + 0][r] = av.x; As[kk + 1][r] = av.y; As[kk + 2][r] = av.z; As[kk + 3][r] = av.w;
        Bs[kk + 0][r] = bv.x; Bs[kk + 1][r] = bv.y; Bs[kk + 2][r] = bv.z; Bs[kk + 3][r] = bv.w;
        __syncthreads();
#pragma unroll
        for (int kki = 0; kki < 16; ++kki) {
            float4 a = *(const float4*)&As[kki][ty * 4];
            float4 b = *(const float4*)&Bs[kki][tx * 4];
            float aa[4] = {a.x, a.y, a.z, a.w};
            float bbv[4] = {b.x, b.y, b.z, b.w};
#pragma unroll
            for (int i = 0; i < 4; ++i)
#pragma unroll
                for (int j = 0; j < 4; ++j)
                    acc[i][j] = fmaf(aa[i], bbv[j], acc[i][j]);
        }
        __syncthreads();
    }
#pragma unroll
    for (int i = 0; i < 4; ++i) {
        const int row = bb + ty * 4 + i;
#pragma unroll
        for (int j = 0; j < 4; ++j) {
            const int col = bn + tx * 4 + j;
            surface[(size_t)row * 1024 + col] = acc[i][j] + b_in[col];
        }
    }
}

// ---------------- Kernel B: cube evolution + output GEMM -----------------
// r11 champion structure (512 thr = 16tx × 32ty, 2 voxels/thread, f32 LDS,
// in-place 4-deep write pipeline, barrier every 4 phases) with the LDS-pipe
// load halved: x-halos now come from neighbor LANES via row-DPP (not from
// LDS halo columns). Layout S[32][34][34]: row = y+1 (y-halo rows 0/33 = 0),
// col = x directly (cols 32/33 pad, unused). Per plane per thread:
// 3× ds_read_b64 (own pair, 8B-aligned, conflict-free per 16-lane quarter)
// + 1× b64 write, was 6 reads + 2 writes. m134: b64 ~6cy -> LDS pipe
// ~384 -> ~192 cy/plane/CU.

#define REP32(M) M(0)M(1)M(2)M(3)M(4)M(5)M(6)M(7)M(8)M(9)M(10)M(11)M(12)M(13)M(14)M(15)M(16)M(17)M(18)M(19)M(20)M(21)M(22)M(23)M(24)M(25)M(26)M(27)M(28)M(29)M(30)M(31)

// out0 (x=2tx): l,c,r = L, w.x, w.y ; out1 (x=2tx+1): w.x, w.y, R
#define RW(aL, aR, wl, wc, wr, L, CX, CY, R)                                   \
    aL = fmaf(wl, L,  aL); aL = fmaf(wc, CX, aL); aL = fmaf(wr, CY, aL);       \
    aR = fmaf(wl, CX, aR); aR = fmaf(wc, CY, aR); aR = fmaf(wr, R,  aR);

// Phase p: barrier every 4; read plane p's 3 own-pair rows; DPP halos;
// write plane p-4 from pend; accumulate aN(out p+1)/aC(out p)/aP(out p-1);
// finalize out p-1 into pend slot (p+2)%3.
#define PLANE(p, q, w4, aN0, aN1, aC0, aC1, aP0, aP1, PD0, PD1) {              \
    if ((p) % 4 == 0) __syncthreads();                                         \
    nb_##p = *(const float2*)&nbias[(p) * 1024 + nboff];                       \
    const float2 w0 = *(const float2*)&S[p][ty + 0][tx2];                      \
    const float2 w1 = *(const float2*)&S[p][ty + 1][tx2];                      \
    const float2 w2 = *(const float2*)&S[p][ty + 2][tx2];                      \
    const float l0 = row_shr1(w0.y), r0 = row_shl1(w0.x);                      \
    const float l1 = row_shr1(w1.y), r1 = row_shl1(w1.x);                      \
    const float l2 = row_shr1(w2.y), r2 = row_shl1(w2.x);                      \
    if ((p) >= 4) {                                                            \
        *(float2*)&S[w4][ty + 1][tx2] = make_float2(PD0, PD1);                 \
    }                                                                          \
    if ((p) < 31) {                                                            \
        RW(aN0, aN1, cw0, cw1, cw2, l0, w0.x, w0.y, r0)                        \
        RW(aN0, aN1, cw3, cw4, cw5, l1, w1.x, w1.y, r1)                        \
        RW(aN0, aN1, cw6, cw7, cw8, l2, w2.x, w2.y, r2)                        \
    }                                                                          \
    RW(aC0, aC1, cw9,  cw10, cw11, l0, w0.x, w0.y, r0)                         \
    RW(aC0, aC1, cw12, cw13, cw14, l1, w1.x, w1.y, r1)                         \
    RW(aC0, aC1, cw15, cw16, cw17, l2, w2.x, w2.y, r2)                         \
    if ((p) >= 1) {                                                            \
        RW(aP0, aP1, cw18, cw19, cw20, l0, w0.x, w0.y, r0)                     \
        RW(aP0, aP1, cw21, cw22, cw23, l1, w1.x, w1.y, r1)                     \
        RW(aP0, aP1, cw24, cw25, cw26, l2, w2.x, w2.y, r2)                     \
        const float pre0 = aP0 + nb_##q.x + (((q) == 0) ? sf0 : 0.0f);         \
        const float pre1 = aP1 + nb_##q.y + (((q) == 0) ? sf1 : 0.0f);         \
        const float h0 = 1.0f - 2.0f * __builtin_amdgcn_rcpf(                  \
            __builtin_amdgcn_exp2f(pre0 * 2.8853900817779268f) + 1.0f);        \
        const float h1 = 1.0f - 2.0f * __builtin_amdgcn_rcpf(                  \
            __builtin_amdgcn_exp2f(pre1 * 2.8853900817779268f) + 1.0f);        \
        PD0 = 0.5f * (cc0 + h0);                                               \
        PD1 = 0.5f * (cc1 + h1);                                               \
        aP0 = 0.0f; aP1 = 0.0f;                                                \
    }                                                                          \
    cc0 = w1.x; cc1 = w1.y;                                                    \
}

__global__ __launch_bounds__(512) void cube_evolve(
    const float* __restrict__ surface,   // [1024][1024]
    const float* __restrict__ conv_w,    // [27]  (kd,ky,kx)
    const float* __restrict__ nbias,     // [32768] (d,y,x)
    const float* __restrict__ W_out,     // [10][32768]
    const float* __restrict__ b_out,     // [10]
    const int*   __restrict__ steps_p,   // [1]
    float* __restrict__ out)             // [1024][10]
{
    __shared__ float S[32][34][34];      // rows 0/33 = y-halo (0); cols 32/33 pad
    __shared__ float red[10][8];

    const int b   = blockIdx.x;
    const int tx  = threadIdx.x;         // 0..15, owns x = 2tx, 2tx+1
    const int ty  = threadIdx.y;         // 0..31
    const int tid = ty * 16 + tx;
    const int tx2 = tx * 2;              // col == x (no x-halo offset)
    const int nboff = ty * 32 + tx2;
    const int steps = steps_p[0];

    // zero state + halos + pads
    for (int i = tid; i < 32 * 34 * 34; i += 512) ((float*)S)[i] = 0.0f;

    // conv weights -> uniform scalars (SGPRs)
    const float cw0  = sgpr_f(conv_w[0]),  cw1  = sgpr_f(conv_w[1]),  cw2  = sgpr_f(conv_w[2]);
    const float cw3  = sgpr_f(conv_w[3]),  cw4  = sgpr_f(conv_w[4]),  cw5  = sgpr_f(conv_w[5]);
    const float cw6  = sgpr_f(conv_w[6]),  cw7  = sgpr_f(conv_w[7]),  cw8  = sgpr_f(conv_w[8]);
    const float cw9  = sgpr_f(conv_w[9]),  cw10 = sgpr_f(conv_w[10]), cw11 = sgpr_f(conv_w[11]);
    const float cw12 = sgpr_f(conv_w[12]), cw13 = sgpr_f(conv_w[13]), cw14 = sgpr_f(conv_w[14]);
    const float cw15 = sgpr_f(conv_w[15]), cw16 = sgpr_f(conv_w[16]), cw17 = sgpr_f(conv_w[17]);
    const float cw18 = sgpr_f(conv_w[18]), cw19 = sgpr_f(conv_w[19]), cw20 = sgpr_f(conv_w[20]);
    const float cw21 = sgpr_f(conv_w[21]), cw22 = sgpr_f(conv_w[22]), cw23 = sgpr_f(conv_w[23]);
    const float cw24 = sgpr_f(conv_w[24]), cw25 = sgpr_f(conv_w[25]), cw26 = sgpr_f(conv_w[26]);

    const float2 sfv = *(const float2*)&surface[(size_t)b * 1024 + nboff];
    const float sf0 = sfv.x, sf1 = sfv.y;

    for (int st = 0; st < steps; ++st) {
#define DECL_NB(d) float2 nb_##d;
        REP32(DECL_NB)
#undef DECL_NB
        float a00 = 0.f, a01 = 0.f, a10 = 0.f, a11 = 0.f, a20 = 0.f, a21 = 0.f;
        float pd00, pd01, pd10, pd11, pd20, pd21;   // pend slots 0,1,2 × 2 vox
        float cc0 = 0.f, cc1 = 0.f;
        // (aN, aC, aP) = slots ((p+1)%3, p%3, (p+2)%3); PD = slot (p+2)%3
        PLANE( 0,  0,  0, a10,a11, a00,a01, a20,a21, pd20,pd21)
        PLANE( 1,  0,  0, a20,a21, a10,a11, a00,a01, pd00,pd01)
        PLANE( 2,  1,  0, a00,a01, a20,a21, a10,a11, pd10,pd11)
        PLANE( 3,  2,  0, a10,a11, a00,a01, a20,a21, pd20,pd21)
        PLANE( 4,  3,  0, a20,a21, a10,a11, a00,a01, pd00,pd01)
        PLANE( 5,  4,  1, a00,a01, a20,a21, a10,a11, pd10,pd11)
        PLANE( 6,  5,  2, a10,a11, a00,a01, a20,a21, pd20,pd21)
        PLANE( 7,  6,  3, a20,a21, a10,a11, a00,a01, pd00,pd01)
        PLANE( 8,  7,  4, a00,a01, a20,a21, a10,a11, pd10,pd11)
        PLANE( 9,  8,  5, a10,a11, a00,a01, a20,a21, pd20,pd21)
        PLANE(10,  9,  6, a20,a21, a10,a11, a00,a01, pd00,pd01)
        PLANE(11, 10,  7, a00,a01, a20,a21, a10,a11, pd10,pd11)
        PLANE(12, 11,  8, a10,a11, a00,a01, a20,a21, pd20,pd21)
        PLANE(13, 12,  9, a20,a21, a10,a11, a00,a01, pd00,pd01)
        PLANE(14, 13, 10, a00,a01, a20,a21, a10,a11, pd10,pd11)
        PLANE(15, 14, 11, a10,a11, a00,a01, a20,a21, pd20,pd21)
        PLANE(16, 15, 12, a20,a21, a10,a11, a00,a01, pd00,pd01)
        PLANE(17, 16, 13, a00,a01, a20,a21, a10,a11, pd10,pd11)
        PLANE(18, 17, 14, a10,a11, a00,a01, a20,a21, pd20,pd21)
        PLANE(19, 18, 15, a20,a21, a10,a11, a00,a01, pd00,pd01)
        PLANE(20, 19, 16, a00,a01, a20,a21, a10,a11, pd10,pd11)
        PLANE(21, 20, 17, a10,a11, a00,a01, a20,a21, pd20,pd21)
        PLANE(22, 21, 18, a20,a21, a10,a11, a00,a01, pd00,pd01)
        PLANE(23, 22, 19, a00,a01, a20,a21, a10,a11, pd10,pd11)
        PLANE(24, 23, 20, a10,a11, a00,a01, a20,a21, pd20,pd21)
        PLANE(25, 24, 21, a20,a21, a10,a11, a00,a01, pd00,pd01)
        PLANE(26, 25, 22, a00,a01, a20,a21, a10,a11, pd10,pd11)
        PLANE(27, 26, 23, a10,a11, a00,a01, a20,a21, pd20,pd21)
        PLANE(28, 27, 24, a20,a21, a10,a11, a00,a01, pd00,pd01)
        PLANE(29, 28, 25, a00,a01, a20,a21, a10,a11, pd10,pd11)
        PLANE(30, 29, 26, a10,a11, a00,a01, a20,a21, pd20,pd21)
        PLANE(31, 30, 27, a20,a21, a10,a11, a00,a01, pd00,pd01)
        { // tail: finalize output 31 (aC of phase 31 = slot1), flush pending
          // planes 28(pd1), 29(pd2), 30(pd0), 31.
            const float pre0 = a10 + nb_31.x;
            const float pre1 = a11 + nb_31.y;
            const float h0 = 1.0f - 2.0f * __builtin_amdgcn_rcpf(
                __builtin_amdgcn_exp2f(pre0 * 2.8853900817779268f) + 1.0f);
            const float h1 = 1.0f - 2.0f * __builtin_amdgcn_rcpf(
                __builtin_amdgcn_exp2f(pre1 * 2.8853900817779268f) + 1.0f);
            const float v310 = 0.5f * (cc0 + h0);
            const float v311 = 0.5f * (cc1 + h1);
            __syncthreads();   // waves may still be reading planes 28..31
            *(float2*)&S[28][ty + 1][tx2] = make_float2(pd10, pd11);
            *(float2*)&S[29][ty + 1][tx2] = make_float2(pd20, pd21);
            *(float2*)&S[30][ty + 1][tx2] = make_float2(pd00, pd01);
            *(float2*)&S[31][ty + 1][tx2] = make_float2(v310, v311);
        }
    }
    __syncthreads();   // state complete & visible

    // ---- fused output GEMM: out[b][o] = sum_flat s * W_out[o][flat] + b_out[o]
    float p0 = 0.f, p1 = 0.f, p2 = 0.f, p3 = 0.f, p4 = 0.f;
    float p5 = 0.f, p6 = 0.f, p7 = 0.f, p8 = 0.f, p9 = 0.f;
    const int base = tid * 4;
#pragma unroll 4
    for (int j = 0; j < 16; ++j) {
        const int idx = base + j * 2048;
        const int d   = idx >> 10;
        const int rem = idx & 1023;
        const int yy  = rem >> 5;
        const int xx  = rem & 31;          // multiple of 4; col == x
        const float2 sva = *(const float2*)&S[d][yy + 1][xx];
        const float2 svb = *(const float2*)&S[d][yy + 1][xx + 2];
#define OACC(o) { const float4 wv = *(const float4*)&W_out[(size_t)(o) * 32768 + idx]; \
        p##o = fmaf(sva.x, wv.x, p##o); p##o = fmaf(sva.y, wv.y, p##o);        \
        p##o = fmaf(svb.x, wv.z, p##o); p##o = fmaf(svb.y, wv.w, p##o); }
        OACC(0) OACC(1) OACC(2) OACC(3) OACC(4)
        OACC(5) OACC(6) OACC(7) OACC(8) OACC(9)
#undef OACC
    }

    const int lane = tid & 63, wvi = tid >> 6;
#define RED(o) { float t = p##o;                                               \
    t += __shfl_down(t, 32, 64); t += __shfl_down(t, 16, 64);                  \
    t += __shfl_down(t, 8, 64);  t += __shfl_down(t, 4, 64);                   \
    t += __shfl_down(t, 2, 64);  t += __shfl_down(t, 1, 64);                   \
    if (lane == 0) red[o][wvi] = t; }
    RED(0) RED(1) RED(2) RED(3) RED(4) RED(5) RED(6) RED(7) RED(8) RED(9)
#undef RED
    __syncthreads();
    if (tid < 10) {
        float sum = b_out[tid];
#pragma unroll
        for (int w8 = 0; w8 < 8; ++w8) sum += red[tid][w8];
        out[(size_t)b * 10 + tid] = sum;
    }
}

// ---------------- launcher ----------------
extern "C" void kernel_launch(void* const* d_in, const int* in_sizes, int n_in,
                              void* d_out, int out_size, void* d_ws, size_t ws_size,
                              hipStream_t stream) {
    const float* x      = (const float*)d_in[0];
    const float* W_in   = (const float*)d_in[1];
    const float* b_in   = (const float*)d_in[2];
    const float* conv_w = (const float*)d_in[3];
    const float* nbias  = (const float*)d_in[4];
    const float* W_out  = (const float*)d_in[5];
    const float* b_out  = (const float*)d_in[6];
    const int*   steps  = (const int*)d_in[7];
    float* out = (float*)d_out;
    float* surface = (float*)d_ws;   // 1024*1024 f32 = 4 MB scratch

    in_gemm<<<dim3(16, 16), 256, 0, stream>>>(x, W_in, b_in, surface);
    cube_evolve<<<1024, dim3(16, 32), 0, stream>>>(surface, conv_w, nbias,
                                                   W_out, b_out, steps, out);
}